// Round 3
// baseline (688.199 us; speedup 1.0000x reference)
//
#include <hip/hip_runtime.h>
#include <stdint.h>

typedef _Float16 f16;
typedef _Float16 half8 __attribute__((ext_vector_type(8)));
typedef _Float16 half4v __attribute__((ext_vector_type(4)));
typedef float f32x4 __attribute__((ext_vector_type(4)));

#define MB (1024ull * 1024ull)
// ---- workspace layout (bytes) ----
#define WT_OFF 0ull            // 3 x 1024x1024 f16 = 6 MiB
#define QH_OFF (6ull * MB)     // 8192x1024 f16 = 16 MiB
#define KH_OFF (22ull * MB)    // 16 MiB
#define VT_OFF (38ull * MB)    // V^T [1024][8192] f16 = 16 MiB
#define PH_OFF (54ull * MB)    // P [8192][8192] f16 = 128 MiB
#define LP2_OFF (182ull * MB)  // lpart [128][8192] f32 = 4 MiB
#define LI_OFF (186ull * MB)   // linv [8192] f32

__device__ __forceinline__ half8 cvt8(float4 a, float4 b) {
  half8 h;
  h[0] = (f16)a.x; h[1] = (f16)a.y; h[2] = (f16)a.z; h[3] = (f16)a.w;
  h[4] = (f16)b.x; h[5] = (f16)b.y; h[6] = (f16)b.z; h[7] = (f16)b.w;
  return h;
}

// async global->LDS, 16B/lane; LDS dst = wave-uniform byte offset (+lane*16 by HW)
__device__ __forceinline__ void gload16(const void* g, uint32_t lds_off) {
  __builtin_amdgcn_global_load_lds(
      (__attribute__((address_space(1))) void*)(uintptr_t)g,
      (__attribute__((address_space(3))) void*)lds_off, 16, 0, 0);
}

// ------------------------------------------------------------------
// K1: transpose-cast weights: Wt[z][dout][din] = (f16)W_z[din][dout]
// ------------------------------------------------------------------
__global__ void k_wt(const float* __restrict__ Wq, const float* __restrict__ Wk,
                     const float* __restrict__ Wv, f16* __restrict__ Wt) {
  __shared__ float tile[32][33];
  const int z = blockIdx.z;
  const float* W = (z == 0) ? Wq : ((z == 1) ? Wk : Wv);
  f16* dst = Wt + z * (1024 * 1024);
  const int tx = threadIdx.x, ty = threadIdx.y;
  const int r0 = blockIdx.y * 32, c0 = blockIdx.x * 32;
#pragma unroll
  for (int i = 0; i < 32; i += 8)
    tile[ty + i][tx] = W[(r0 + ty + i) * 1024 + c0 + tx];
  __syncthreads();
#pragma unroll
  for (int i = 0; i < 32; i += 8)
    dst[(c0 + ty + i) * 1024 + r0 + tx] = (f16)tile[tx][ty + i];
}

// ------------------------------------------------------------------
// K2: projection GEMM (fp32 X cast on the fly). Unchanged from R2.
// ------------------------------------------------------------------
__launch_bounds__(256, 2)
__global__ void k_proj(const float* __restrict__ X, const f16* __restrict__ Wt,
                       f16* __restrict__ Qh, f16* __restrict__ Kh, f16* __restrict__ Vt) {
  __shared__ f16 As[2][128][40];
  __shared__ f16 Bs[2][128][40];
  const int z = blockIdx.z;
  const f16* Wz = Wt + z * (1024 * 1024);
  const int m0 = blockIdx.x * 128, n0 = blockIdx.y * 128;
  const int t = threadIdx.x;
  const int w = t >> 6, l = t & 63;
  const int wr = w >> 1, wc = w & 1;
  const int lr = l & 15, lk = (l >> 4) * 8;
  const int sr = t >> 1, sh = t & 1;

  const float* xsrc = X + (m0 + sr) * 1024 + sh * 16;
  const f16*   bsrc = Wz + (n0 + sr) * 1024 + sh * 16;

  f32x4 acc[4][4] = {};

  {
    float4 v0 = *(const float4*)(xsrc + 0);
    float4 v1 = *(const float4*)(xsrc + 4);
    float4 v2 = *(const float4*)(xsrc + 8);
    float4 v3 = *(const float4*)(xsrc + 12);
    *(half8*)(&As[0][sr][sh * 16 + 0]) = cvt8(v0, v1);
    *(half8*)(&As[0][sr][sh * 16 + 8]) = cvt8(v2, v3);
    *(half8*)(&Bs[0][sr][sh * 16 + 0]) = *(const half8*)(bsrc + 0);
    *(half8*)(&Bs[0][sr][sh * 16 + 8]) = *(const half8*)(bsrc + 8);
  }
  __syncthreads();

#pragma unroll 1
  for (int kt = 0; kt < 32; ++kt) {
    const int cur = kt & 1;
    float4 v0, v1, v2, v3;
    half8 b0, b1;
    if (kt < 31) {
      const float* xs = xsrc + (kt + 1) * 32;
      v0 = *(const float4*)(xs + 0);
      v1 = *(const float4*)(xs + 4);
      v2 = *(const float4*)(xs + 8);
      v3 = *(const float4*)(xs + 12);
      const f16* bs = bsrc + (kt + 1) * 32;
      b0 = *(const half8*)(bs + 0);
      b1 = *(const half8*)(bs + 8);
    }
    half8 af[4], bf[4];
#pragma unroll
    for (int mi = 0; mi < 4; ++mi)
      af[mi] = *(const half8*)(&As[cur][wr * 64 + mi * 16 + lr][lk]);
#pragma unroll
    for (int ni = 0; ni < 4; ++ni)
      bf[ni] = *(const half8*)(&Bs[cur][wc * 64 + ni * 16 + lr][lk]);
#pragma unroll
    for (int mi = 0; mi < 4; ++mi)
#pragma unroll
      for (int ni = 0; ni < 4; ++ni)
        acc[mi][ni] = __builtin_amdgcn_mfma_f32_16x16x32_f16(af[mi], bf[ni], acc[mi][ni], 0, 0, 0);
    if (kt < 31) {
      *(half8*)(&As[cur ^ 1][sr][sh * 16 + 0]) = cvt8(v0, v1);
      *(half8*)(&As[cur ^ 1][sr][sh * 16 + 8]) = cvt8(v2, v3);
      *(half8*)(&Bs[cur ^ 1][sr][sh * 16 + 0]) = b0;
      *(half8*)(&Bs[cur ^ 1][sr][sh * 16 + 8]) = b1;
    }
    __syncthreads();
  }

  if (z < 2) {
    f16* dst = (z == 0) ? Qh : Kh;
#pragma unroll
    for (int mi = 0; mi < 4; ++mi)
#pragma unroll
      for (int ni = 0; ni < 4; ++ni) {
        const int row = m0 + wr * 64 + mi * 16 + (l >> 4) * 4;
        const int col = n0 + wc * 64 + ni * 16 + lr;
#pragma unroll
        for (int r = 0; r < 4; ++r)
          dst[(row + r) * 1024 + col] = (f16)acc[mi][ni][r];
      }
  } else {
#pragma unroll
    for (int mi = 0; mi < 4; ++mi)
#pragma unroll
      for (int ni = 0; ni < 4; ++ni) {
        const int row = m0 + wr * 64 + mi * 16 + (l >> 4) * 4;
        const int col = n0 + wc * 64 + ni * 16 + lr;
        half4v v = {(f16)acc[mi][ni][0], (f16)acc[mi][ni][1],
                    (f16)acc[mi][ni][2], (f16)acc[mi][ni][3]};
        *(half4v*)(&Vt[col * 8192 + row]) = v;
      }
  }
}

// ------------------------------------------------------------------
// K3/K5: 256-row-tile deep-pipelined GEMM (T2 swizzle + counted vmcnt + setprio).
// BM=256 fixed. BN/WN template. BK=64 split into 2 ks-regions of 32 k each.
// Region = [rows][32k] f16, LDS-linear rows of 64B, slot-swizzled (slot^=row&3).
// Phases/K-tile: P=4 (sexp: (ks,mh), 16 MFMA) or P=2 (pv: ks, 16 MFMA).
// Per phase: ds_read frags | stage 1-2 regions via gload_lds | counted vmcnt |
// barrier | setprio(1) MFMA setprio(0) | barrier.  vmcnt never 0 in loop.
// PVE=false: epilogue exp2 -> P f16 (via LDS), row-sum partials -> lpart.
// PVE=true:  epilogue scale by linv -> out f32.
// ------------------------------------------------------------------
template <int BN, int WN, int NK, int LDA, int LDB, bool PVE>
__launch_bounds__(512, 2)
__global__ void k_g8(const f16* __restrict__ Ag, const f16* __restrict__ Bg,
                     f16* __restrict__ Pg, float* __restrict__ lpart,
                     const float* __restrict__ linv, float* __restrict__ outp) {
  constexpr int WM = 8 / WN;           // 2 (sexp) or 4 (pv)
  constexpr int WTM = 256 / WM;        // 128 or 64
  constexpr int NRM = WTM / 16;        // 8 or 4
  constexpr int P = NRM / 2;           // phases per K-tile: 4 or 2
  constexpr int MH = (P == 4) ? 4 : NRM;  // mi per phase = 4
  constexpr int BKS = BN * 64;         // bytes per B ks-region
  constexpr int BLO = (BN == 256) ? 2 : 1;
  constexpr int BBASE = 65536;         // A: 2 buf x 2 ks x 16KB
  constexpr int NTN = (PVE ? 1024 : 8192) / BN;
  constexpr int CPX = (32 * NTN) / 8;

  __shared__ __align__(128) char smem[BBASE + 4 * BKS];

  const int t = threadIdx.x;
  const int w = t >> 6, l = t & 63;
  const int lr = l & 15, g = l >> 4;
  const int wr = w / WN, wc = w % WN;
  const int bid = blockIdx.x;
  const int swz = (bid & 7) * CPX + (bid >> 3);   // XCD-aware, bijective (nwg%8==0)
  const int mt = swz / NTN, ntl = swz % NTN;
  const int m0 = mt * 256, n0 = ntl * BN;

  const uint32_t lds0 = (uint32_t)(uintptr_t)(void*)smem;
  const int lq = l >> 2, ls = l & 3;
  const int sw = (ls ^ (lq & 3)) << 3;            // pre-swizzled source k-offset

  auto stA = [&](int kS, int ks, int b) {
#pragma unroll
    for (int j = 0; j < 2; ++j) {
      const int rl = w * 32 + j * 16 + lq;
      gload16(Ag + (size_t)(m0 + rl) * LDA + kS * 64 + ks * 32 + sw,
              lds0 + b * 32768 + ks * 16384 + w * 2048 + j * 1024);
    }
  };
  auto stB = [&](int kS, int ks, int b) {
#pragma unroll
    for (int j = 0; j < BLO; ++j) {
      const int rl = w * (16 * BLO) + j * 16 + lq;
      gload16(Bg + (size_t)(n0 + rl) * LDB + kS * 64 + ks * 32 + sw,
              lds0 + BBASE + b * (2 * BKS) + ks * BKS + w * (1024 * BLO) + j * 1024);
    }
  };

  f32x4 acc[NRM][4] = {};

  // ---- prologue: stage kt0 fully + kt1 minus the region the loop stages first ----
  if constexpr (P == 4) {
    stA(0, 0, 0); stB(0, 0, 0); stA(0, 1, 0); stB(0, 1, 0);
    stB(1, 0, 1); stA(1, 0, 1); stB(1, 1, 1);   // loop (kt=0,j=0) adds A_ks1(1)
  } else {
    stA(0, 0, 0); stB(0, 0, 0); stA(0, 1, 0); stB(0, 1, 0);
    stA(1, 0, 1); stB(1, 0, 1);                 // loop (kt=0,j=0) adds ks1(1)
  }
  asm volatile("s_waitcnt vmcnt(0)");
  __builtin_amdgcn_s_barrier();

  const int rdsw = (g ^ (lr & 3)) << 4;          // swizzled read slot (bytes)

#pragma unroll 1
  for (int kt = 0; kt < NK; ++kt) {
    const int b = kt & 1;
    const int kA1 = (kt + 1 < NK) ? kt + 1 : kt; // src clamp keeps vmcnt math uniform
    const int kN = (kt + 2 < NK) ? kt + 2 : kt;
    half8 bfk[4];
#pragma unroll
    for (int j = 0; j < P; ++j) {
      const int ks = (P == 4) ? (j >> 1) : j;
      const int mh = (P == 4) ? (j & 1) : 0;
      if (P == 2 || mh == 0) {
#pragma unroll
        for (int ni = 0; ni < 4; ++ni) {
          const int rb = wc * 64 + ni * 16 + lr;
          bfk[ni] = *(const half8*)(smem + BBASE + b * (2 * BKS) + ks * BKS + rb * 64 + rdsw);
        }
      }
      half8 af[MH];
#pragma unroll
      for (int mi = 0; mi < MH; ++mi) {
        const int ra = wr * WTM + mh * 64 + mi * 16 + lr;
        af[mi] = *(const half8*)(smem + b * 32768 + ks * 16384 + ra * 64 + rdsw);
      }
      if constexpr (P == 4) {
        if (j == 0) stA(kA1, 1, b ^ 1);          // into freed other-buf region
        else if (j == 1) stB(kN, 0, b);          // cur-buf B_ks0 freed at j=0
        else if (j == 2) stA(kN, 0, b);          // cur-buf A_ks0 freed at j=1
        else stB(kN, 1, b);                      // cur-buf B_ks1 freed at j=2
        if (j & 1) asm volatile("s_waitcnt vmcnt(10)");  // 5 stages x 2 loads in flight
      } else {
        if (j == 0) { stA(kA1, 1, b ^ 1); stB(kA1, 1, b ^ 1); }
        else { stA(kN, 0, b); stB(kN, 0, b); }
        asm volatile("s_waitcnt vmcnt(6)");      // 2 stage-pairs x (2+1) loads in flight
      }
      __builtin_amdgcn_s_barrier();
      __builtin_amdgcn_s_setprio(1);
#pragma unroll
      for (int mi = 0; mi < MH; ++mi)
#pragma unroll
        for (int ni = 0; ni < 4; ++ni)
          acc[mh * MH + mi][ni] =
              __builtin_amdgcn_mfma_f32_16x16x32_f16(af[mi], bfk[ni], acc[mh * MH + mi][ni], 0, 0, 0);
      __builtin_amdgcn_s_setprio(0);
      __builtin_amdgcn_s_barrier();
    }
  }

  asm volatile("s_waitcnt vmcnt(0)");  // drain tail DMA before LDS reuse / exit

  if constexpr (!PVE) {
    // p = exp(S/32) = 2^(S*log2e/32); per-row partial sums
    float rs[NRM][4];
#pragma unroll
    for (int mi = 0; mi < NRM; ++mi)
#pragma unroll
      for (int r = 0; r < 4; ++r) rs[mi][r] = 0.f;
#pragma unroll
    for (int mi = 0; mi < NRM; ++mi)
#pragma unroll
      for (int ni = 0; ni < 4; ++ni)
#pragma unroll
        for (int r = 0; r < 4; ++r) {
          const float p = exp2f(acc[mi][ni][r] * 0.045084222f);
          acc[mi][ni][r] = p;
          rs[mi][r] += p;
        }
#pragma unroll
    for (int mi = 0; mi < NRM; ++mi)
#pragma unroll
      for (int r = 0; r < 4; ++r) {
        float v = rs[mi][r];
        v += __shfl_xor(v, 1); v += __shfl_xor(v, 2);
        v += __shfl_xor(v, 4); v += __shfl_xor(v, 8);
        rs[mi][r] = v;
      }
    if (lr == 0) {
#pragma unroll
      for (int mi = 0; mi < NRM; ++mi)
#pragma unroll
        for (int r = 0; r < 4; ++r)
          lpart[(size_t)(ntl * WN + wc) * 8192 + m0 + wr * WTM + mi * 16 + g * 4 + r] = rs[mi][r];
    }
    __syncthreads();
    // P tile 256x256 f16 -> global via LDS, 4 chunks of 64 rows (32KB)
#pragma unroll 1
    for (int c = 0; c < 4; ++c) {
      if (wr == (c >> 1)) {
        const int mib = (c & 1) * 4;
#pragma unroll
        for (int mi = 0; mi < 4; ++mi)
#pragma unroll
          for (int ni = 0; ni < 4; ++ni)
#pragma unroll
            for (int r = 0; r < 4; ++r)
              *(f16*)(smem + (mi * 16 + g * 4 + r) * 512 + (wc * 64 + ni * 16 + lr) * 2) =
                  (f16)acc[mib + mi][ni][r];
      }
      __syncthreads();
      {
        const int row = t >> 3, sl = t & 7;
#pragma unroll
        for (int q = 0; q < 4; ++q)
          *(int4*)(Pg + (size_t)(m0 + c * 64 + row) * 8192 + n0 + sl * 32 + q * 8) =
              *(const int4*)(smem + row * 512 + sl * 64 + q * 16);
      }
      __syncthreads();
    }
  } else {
#pragma unroll
    for (int mi = 0; mi < NRM; ++mi) {
#pragma unroll
      for (int r = 0; r < 4; ++r) {
        const int rowg = m0 + wr * WTM + mi * 16 + g * 4 + r;
        const float iv = linv[rowg];
#pragma unroll
        for (int ni = 0; ni < 4; ++ni)
          outp[(size_t)rowg * 1024 + n0 + wc * 64 + ni * 16 + lr] = acc[mi][ni][r] * iv;
      }
    }
  }
}

// ------------------------------------------------------------------
// K4: reduce 128 row-sum partials -> inverse row sums
// ------------------------------------------------------------------
__global__ void k_lred(const float* __restrict__ lpart, float* __restrict__ linv) {
  const int r = blockIdx.x * 256 + threadIdx.x;
  float s = 0.f;
#pragma unroll
  for (int i = 0; i < 128; ++i) s += lpart[(size_t)i * 8192 + r];
  linv[r] = 1.0f / s;
}

// ------------------------------------------------------------------
extern "C" void kernel_launch(void* const* d_in, const int* in_sizes, int n_in,
                              void* d_out, int out_size, void* d_ws, size_t ws_size,
                              hipStream_t stream) {
  (void)in_sizes; (void)n_in; (void)out_size; (void)ws_size;
  const float* X  = (const float*)d_in[0];
  const float* Wq = (const float*)d_in[1];
  const float* Wk = (const float*)d_in[2];
  const float* Wv = (const float*)d_in[3];
  char* ws = (char*)d_ws;
  f16* Wt = (f16*)(ws + WT_OFF);
  f16* Qh = (f16*)(ws + QH_OFF);
  f16* Kh = (f16*)(ws + KH_OFF);
  f16* Vt = (f16*)(ws + VT_OFF);
  f16* Ph = (f16*)(ws + PH_OFF);
  float* lpart = (float*)(ws + LP2_OFF);
  float* linv  = (float*)(ws + LI_OFF);
  float* out = (float*)d_out;

  k_wt  <<<dim3(32, 32, 3), dim3(32, 8), 0, stream>>>(Wq, Wk, Wv, Wt);
  k_proj<<<dim3(64, 8, 3),  dim3(256),   0, stream>>>(X, Wt, Qh, Kh, Vt);
  // S = Q@K^T -> P = exp(S/32): M=N=8192, K=1024; 32x32 tiles of 256^2
  k_g8<256, 4, 16, 1024, 1024, false><<<dim3(1024), dim3(512), 0, stream>>>(
      Qh, Kh, Ph, lpart, nullptr, nullptr);
  k_lred<<<dim3(32), dim3(256), 0, stream>>>(lpart, linv);
  // out = (P@V) * linv: M=8192, N=1024, K=8192; 32x8 tiles of 256x128
  k_g8<128, 2, 128, 8192, 8192, true><<<dim3(256), dim3(512), 0, stream>>>(
      Ph, Vt, nullptr, nullptr, linv, out);
}

// Round 4
// 456.784 us; speedup vs baseline: 1.5066x; 1.5066x over previous
//
#include <hip/hip_runtime.h>
#include <stdint.h>

typedef _Float16 f16;
typedef _Float16 half8 __attribute__((ext_vector_type(8)));
typedef _Float16 half4v __attribute__((ext_vector_type(4)));
typedef float f32x4 __attribute__((ext_vector_type(4)));

#define MB (1024ull * 1024ull)
// ---- workspace layout (bytes) ----
#define WT_OFF 0ull            // 3 x 1024x1024 f16 = 6 MiB
#define QH_OFF (6ull * MB)     // 8192x1024 f16 = 16 MiB
#define KH_OFF (22ull * MB)    // 16 MiB
#define VT_OFF (38ull * MB)    // V^T [1024][8192] f16 = 16 MiB
#define PH_OFF (54ull * MB)    // P [8192][8192] f16 = 128 MiB
#define LP2_OFF (182ull * MB)  // lpart [128][8192] f32 = 4 MiB
#define LI_OFF (186ull * MB)   // linv [8192] f32

__device__ __forceinline__ half8 cvt8(float4 a, float4 b) {
  half8 h;
  h[0] = (f16)a.x; h[1] = (f16)a.y; h[2] = (f16)a.z; h[3] = (f16)a.w;
  h[4] = (f16)b.x; h[5] = (f16)b.y; h[6] = (f16)b.z; h[7] = (f16)b.w;
  return h;
}

// async global->LDS, 16B/lane; LDS dst = wave-uniform byte offset (+lane*16 by HW)
__device__ __forceinline__ void gload16(const void* g, uint32_t lds_off) {
  __builtin_amdgcn_global_load_lds(
      (__attribute__((address_space(1))) void*)(uintptr_t)g,
      (__attribute__((address_space(3))) void*)lds_off, 16, 0, 0);
}

// ------------------------------------------------------------------
// K1: transpose-cast weights: Wt[z][dout][din] = (f16)W_z[din][dout]
// ------------------------------------------------------------------
__global__ void k_wt(const float* __restrict__ Wq, const float* __restrict__ Wk,
                     const float* __restrict__ Wv, f16* __restrict__ Wt) {
  __shared__ float tile[32][33];
  const int z = blockIdx.z;
  const float* W = (z == 0) ? Wq : ((z == 1) ? Wk : Wv);
  f16* dst = Wt + z * (1024 * 1024);
  const int tx = threadIdx.x, ty = threadIdx.y;
  const int r0 = blockIdx.y * 32, c0 = blockIdx.x * 32;
#pragma unroll
  for (int i = 0; i < 32; i += 8)
    tile[ty + i][tx] = W[(r0 + ty + i) * 1024 + c0 + tx];
  __syncthreads();
#pragma unroll
  for (int i = 0; i < 32; i += 8)
    dst[(c0 + ty + i) * 1024 + r0 + tx] = (f16)tile[tx][ty + i];
}

// ------------------------------------------------------------------
// K2: projection GEMM (fp32 X cast on the fly). Proven in R2; unchanged.
// ------------------------------------------------------------------
__launch_bounds__(256, 2)
__global__ void k_proj(const float* __restrict__ X, const f16* __restrict__ Wt,
                       f16* __restrict__ Qh, f16* __restrict__ Kh, f16* __restrict__ Vt) {
  __shared__ f16 As[2][128][40];
  __shared__ f16 Bs[2][128][40];
  const int z = blockIdx.z;
  const f16* Wz = Wt + z * (1024 * 1024);
  const int m0 = blockIdx.x * 128, n0 = blockIdx.y * 128;
  const int t = threadIdx.x;
  const int w = t >> 6, l = t & 63;
  const int wr = w >> 1, wc = w & 1;
  const int lr = l & 15, lk = (l >> 4) * 8;
  const int sr = t >> 1, sh = t & 1;

  const float* xsrc = X + (m0 + sr) * 1024 + sh * 16;
  const f16*   bsrc = Wz + (n0 + sr) * 1024 + sh * 16;

  f32x4 acc[4][4] = {};

  {
    float4 v0 = *(const float4*)(xsrc + 0);
    float4 v1 = *(const float4*)(xsrc + 4);
    float4 v2 = *(const float4*)(xsrc + 8);
    float4 v3 = *(const float4*)(xsrc + 12);
    *(half8*)(&As[0][sr][sh * 16 + 0]) = cvt8(v0, v1);
    *(half8*)(&As[0][sr][sh * 16 + 8]) = cvt8(v2, v3);
    *(half8*)(&Bs[0][sr][sh * 16 + 0]) = *(const half8*)(bsrc + 0);
    *(half8*)(&Bs[0][sr][sh * 16 + 8]) = *(const half8*)(bsrc + 8);
  }
  __syncthreads();

#pragma unroll 1
  for (int kt = 0; kt < 32; ++kt) {
    const int cur = kt & 1;
    float4 v0, v1, v2, v3;
    half8 b0, b1;
    if (kt < 31) {
      const float* xs = xsrc + (kt + 1) * 32;
      v0 = *(const float4*)(xs + 0);
      v1 = *(const float4*)(xs + 4);
      v2 = *(const float4*)(xs + 8);
      v3 = *(const float4*)(xs + 12);
      const f16* bs = bsrc + (kt + 1) * 32;
      b0 = *(const half8*)(bs + 0);
      b1 = *(const half8*)(bs + 8);
    }
    half8 af[4], bf[4];
#pragma unroll
    for (int mi = 0; mi < 4; ++mi)
      af[mi] = *(const half8*)(&As[cur][wr * 64 + mi * 16 + lr][lk]);
#pragma unroll
    for (int ni = 0; ni < 4; ++ni)
      bf[ni] = *(const half8*)(&Bs[cur][wc * 64 + ni * 16 + lr][lk]);
#pragma unroll
    for (int mi = 0; mi < 4; ++mi)
#pragma unroll
      for (int ni = 0; ni < 4; ++ni)
        acc[mi][ni] = __builtin_amdgcn_mfma_f32_16x16x32_f16(af[mi], bf[ni], acc[mi][ni], 0, 0, 0);
    if (kt < 31) {
      *(half8*)(&As[cur ^ 1][sr][sh * 16 + 0]) = cvt8(v0, v1);
      *(half8*)(&As[cur ^ 1][sr][sh * 16 + 8]) = cvt8(v2, v3);
      *(half8*)(&Bs[cur ^ 1][sr][sh * 16 + 0]) = b0;
      *(half8*)(&Bs[cur ^ 1][sr][sh * 16 + 8]) = b1;
    }
    __syncthreads();
  }

  if (z < 2) {
    f16* dst = (z == 0) ? Qh : Kh;
#pragma unroll
    for (int mi = 0; mi < 4; ++mi)
#pragma unroll
      for (int ni = 0; ni < 4; ++ni) {
        const int row = m0 + wr * 64 + mi * 16 + (l >> 4) * 4;
        const int col = n0 + wc * 64 + ni * 16 + lr;
#pragma unroll
        for (int r = 0; r < 4; ++r)
          dst[(row + r) * 1024 + col] = (f16)acc[mi][ni][r];
      }
  } else {
#pragma unroll
    for (int mi = 0; mi < 4; ++mi)
#pragma unroll
      for (int ni = 0; ni < 4; ++ni) {
        const int row = m0 + wr * 64 + mi * 16 + (l >> 4) * 4;
        const int col = n0 + wc * 64 + ni * 16 + lr;
        half4v v = {(f16)acc[mi][ni][0], (f16)acc[mi][ni][1],
                    (f16)acc[mi][ni][2], (f16)acc[mi][ni][3]};
        *(half4v*)(&Vt[col * 8192 + row]) = v;
      }
  }
}

// ------------------------------------------------------------------
// K3/K5: unified P=2 deep-pipeline GEMM. BM=256, 8 waves (512 thr).
// WN=4: wave tile 128x64 (sexp, 32 MFMA/phase); WN=2: 64x64 (pv, 16/phase).
// BK=64 split in 2 ks-regions of 32k; region rows of 64B, slot-swizzled
// with slot ^= (row>>1)&3 (conflict-free for 64B row stride, R3 errata).
// Phase: ds_read frags | stage {A,B} future region | vmcnt(2L) | barrier |
// setprio(1) MFMA setprio(0) | barrier. Stage schedule: ph0 -> ks1[b^1]
// of kt+1; ph1 -> ks0[b] of kt+2 (3-phase issue->read distance; clamped
// idempotent tail). vmcnt never 0 inside the loop.
// ------------------------------------------------------------------
template <int WN, int BN, int NK, int LDA, int LDB, bool PVE>
__launch_bounds__(512, 2)
__global__ void k_g8(const f16* __restrict__ Ag, const f16* __restrict__ Bg,
                     f16* __restrict__ Pg, float* __restrict__ lpart,
                     const float* __restrict__ linv, float* __restrict__ outp) {
  constexpr int WM = 8 / WN;           // 2 (sexp) / 4 (pv)
  constexpr int WTM = 256 / WM;        // 128 / 64
  constexpr int NRM = WTM / 16;        // 8 / 4
  constexpr int BKS = BN * 64;         // bytes per B ks-region
  constexpr int NLB = BN / 128;        // stB gload16 count: 2 / 1
  constexpr int BBASE = 65536;         // A: 2buf x 2ks x 16KB
  constexpr int VM = 2 * (2 + NLB);    // counted vmcnt: 8 / 6
  constexpr int NTN = (PVE ? 1024 : 8192) / BN;
  constexpr int CPX = (32 * NTN) / 8;

  __shared__ __align__(128) char smem[BBASE + 4 * BKS];

  const int t = threadIdx.x;
  const int w = t >> 6, l = t & 63;
  const int lr = l & 15, g = l >> 4;
  const int wr = w / WN, wc = w % WN;
  const int bid = blockIdx.x;
  const int swz = (bid & 7) * CPX + (bid >> 3);   // XCD-aware, bijective (nwg%8==0)
  const int mt = swz / NTN, ntl = swz % NTN;
  const int m0 = mt * 256, n0 = ntl * BN;

  const uint32_t lds0 = (uint32_t)(uintptr_t)(void*)smem;
  const int lq = l >> 2, ls = l & 3;
  const int sw = (ls ^ ((lq >> 1) & 3)) << 3;     // pre-swizzled source k-off (halves)
  const int rdsw = (g ^ ((lr >> 1) & 3)) << 4;    // swizzled read slot (bytes)

  auto stA = [&](int kS, int ks, int b) {
#pragma unroll
    for (int j = 0; j < 2; ++j) {
      const int rl = w * 32 + j * 16 + lq;
      gload16(Ag + (size_t)(m0 + rl) * LDA + kS * 64 + ks * 32 + sw,
              lds0 + b * 32768 + ks * 16384 + (w * 2 + j) * 1024);
    }
  };
  auto stB = [&](int kS, int ks, int b) {
#pragma unroll
    for (int j = 0; j < NLB; ++j) {
      const int rl = w * (16 * NLB) + j * 16 + lq;
      gload16(Bg + (size_t)(n0 + rl) * LDB + kS * 64 + ks * 32 + sw,
              lds0 + BBASE + b * (2 * BKS) + ks * BKS + (w * NLB + j) * 1024);
    }
  };

  f32x4 acc[NRM][4] = {};

  // prologue: kt0 both ks, kt1 ks0; drain the pair read first
  stA(0, 0, 0); stB(0, 0, 0);
  stA(0, 1, 0); stB(0, 1, 0);
  stA(1, 0, 1); stB(1, 0, 1);
  asm volatile("s_waitcnt vmcnt(%0)" :: "i"(VM));
  __builtin_amdgcn_s_barrier();

#pragma unroll 1
  for (int kt = 0; kt < NK; ++kt) {
    const int b = kt & 1;
    const int k1 = (kt + 1 < NK) ? kt + 1 : kt;  // clamp keeps tail idempotent
    const int k2 = (kt + 2 < NK) ? kt + 2 : kt;
#pragma unroll
    for (int ks = 0; ks < 2; ++ks) {
      half8 af[NRM], bf[4];
#pragma unroll
      for (int mi = 0; mi < NRM; ++mi)
        af[mi] = *(const half8*)(smem + b * 32768 + ks * 16384 +
                                 (wr * WTM + mi * 16 + lr) * 64 + rdsw);
#pragma unroll
      for (int ni = 0; ni < 4; ++ni)
        bf[ni] = *(const half8*)(smem + BBASE + b * (2 * BKS) + ks * BKS +
                                 (wc * 64 + ni * 16 + lr) * 64 + rdsw);
      if (ks == 0) { stA(k1, 1, b ^ 1); stB(k1, 1, b ^ 1); }
      else         { stA(k2, 0, b);     stB(k2, 0, b); }
      asm volatile("s_waitcnt vmcnt(%0)" :: "i"(VM));
      __builtin_amdgcn_s_barrier();
      __builtin_amdgcn_s_setprio(1);
#pragma unroll
      for (int mi = 0; mi < NRM; ++mi)
#pragma unroll
        for (int ni = 0; ni < 4; ++ni)
          acc[mi][ni] = __builtin_amdgcn_mfma_f32_16x16x32_f16(af[mi], bf[ni], acc[mi][ni], 0, 0, 0);
      __builtin_amdgcn_s_setprio(0);
      __builtin_amdgcn_s_barrier();
    }
  }
  asm volatile("s_waitcnt vmcnt(0)");  // drain tail DMA before LDS reuse / exit
  __builtin_amdgcn_s_barrier();

  if constexpr (!PVE) {
    // p = exp(S/32) = 2^(S*log2(e)/32); per-row partials; P tile via LDS
    float rs[NRM][4];
#pragma unroll
    for (int mi = 0; mi < NRM; ++mi)
#pragma unroll
      for (int r = 0; r < 4; ++r) rs[mi][r] = 0.f;
#pragma unroll
    for (int mi = 0; mi < NRM; ++mi)
#pragma unroll
      for (int ni = 0; ni < 4; ++ni)
#pragma unroll
        for (int r = 0; r < 4; ++r) {
          const float p = exp2f(acc[mi][ni][r] * 0.045084222f);
          acc[mi][ni][r] = p;
          rs[mi][r] += p;
        }
#pragma unroll
    for (int mi = 0; mi < NRM; ++mi)
#pragma unroll
      for (int r = 0; r < 4; ++r) {
        float v = rs[mi][r];
        v += __shfl_xor(v, 1); v += __shfl_xor(v, 2);
        v += __shfl_xor(v, 4); v += __shfl_xor(v, 8);
        rs[mi][r] = v;
      }
    if (lr == 0) {
#pragma unroll
      for (int mi = 0; mi < NRM; ++mi)
#pragma unroll
        for (int r = 0; r < 4; ++r)
          lpart[(size_t)(ntl * WN + wc) * 8192 + m0 + wr * WTM + mi * 16 + g * 4 + r] = rs[mi][r];
    }
    // stage full 256x256 f16 P tile into the (drained) 128KB LDS
#pragma unroll
    for (int mi = 0; mi < NRM; ++mi)
#pragma unroll
      for (int ni = 0; ni < 4; ++ni)
#pragma unroll
        for (int r = 0; r < 4; ++r)
          *(f16*)(smem + (wr * WTM + mi * 16 + g * 4 + r) * 512 +
                  (wc * 64 + ni * 16 + lr) * 2) = (f16)acc[mi][ni][r];
    __syncthreads();
    {
      const int row = t >> 1, sl = t & 1;
#pragma unroll
      for (int q = 0; q < 16; ++q)
        *(int4*)(Pg + (size_t)(m0 + row) * 8192 + n0 + sl * 128 + q * 8) =
            *(const int4*)(smem + row * 512 + sl * 256 + q * 16);
    }
  } else {
#pragma unroll
    for (int mi = 0; mi < NRM; ++mi) {
#pragma unroll
      for (int r = 0; r < 4; ++r) {
        const int rowg = m0 + wr * WTM + mi * 16 + g * 4 + r;
        const float iv = linv[rowg];
#pragma unroll
        for (int ni = 0; ni < 4; ++ni)
          outp[(size_t)rowg * 1024 + n0 + wc * 64 + ni * 16 + lr] = acc[mi][ni][r] * iv;
      }
    }
  }
}

// ------------------------------------------------------------------
// K4: reduce 128 row-sum partials -> inverse row sums
// ------------------------------------------------------------------
__global__ void k_lred(const float* __restrict__ lpart, float* __restrict__ linv) {
  const int r = blockIdx.x * 256 + threadIdx.x;
  float s = 0.f;
#pragma unroll
  for (int i = 0; i < 128; ++i) s += lpart[(size_t)i * 8192 + r];
  linv[r] = 1.0f / s;
}

// ------------------------------------------------------------------
extern "C" void kernel_launch(void* const* d_in, const int* in_sizes, int n_in,
                              void* d_out, int out_size, void* d_ws, size_t ws_size,
                              hipStream_t stream) {
  (void)in_sizes; (void)n_in; (void)out_size; (void)ws_size;
  const float* X  = (const float*)d_in[0];
  const float* Wq = (const float*)d_in[1];
  const float* Wk = (const float*)d_in[2];
  const float* Wv = (const float*)d_in[3];
  char* ws = (char*)d_ws;
  f16* Wt = (f16*)(ws + WT_OFF);
  f16* Qh = (f16*)(ws + QH_OFF);
  f16* Kh = (f16*)(ws + KH_OFF);
  f16* Vt = (f16*)(ws + VT_OFF);
  f16* Ph = (f16*)(ws + PH_OFF);
  float* lpart = (float*)(ws + LP2_OFF);
  float* linv  = (float*)(ws + LI_OFF);
  float* out = (float*)d_out;

  k_wt  <<<dim3(32, 32, 3), dim3(32, 8), 0, stream>>>(Wq, Wk, Wv, Wt);
  k_proj<<<dim3(64, 8, 3),  dim3(256),   0, stream>>>(X, Wt, Qh, Kh, Vt);
  // S = Q@K^T -> P = exp(S/32): M=N=8192, K=1024; 32x32 tiles of 256^2
  k_g8<4, 256, 16, 1024, 1024, false><<<dim3(1024), dim3(512), 0, stream>>>(
      Qh, Kh, Ph, lpart, nullptr, nullptr);
  k_lred<<<dim3(32), dim3(256), 0, stream>>>(lpart, linv);
  // out = (P@V) * linv: M=8192, N=1024, K=8192; 32x8 tiles of 256x128
  k_g8<2, 128, 128, 8192, 8192, true><<<dim3(256), dim3(512), 0, stream>>>(
      Ph, Vt, nullptr, nullptr, linv, out);
}

// Round 5
// 456.161 us; speedup vs baseline: 1.5087x; 1.0014x over previous
//
#include <hip/hip_runtime.h>
#include <stdint.h>

typedef _Float16 f16;
typedef _Float16 half8 __attribute__((ext_vector_type(8)));
typedef _Float16 half4v __attribute__((ext_vector_type(4)));
typedef float f32x4 __attribute__((ext_vector_type(4)));

#define MB (1024ull * 1024ull)
// ---- workspace layout (bytes) ----
#define WT_OFF 0ull            // 3 x 1024x1024 f16 = 6 MiB
#define QH_OFF (6ull * MB)     // 8192x1024 f16 = 16 MiB
#define KH_OFF (22ull * MB)    // 16 MiB
#define VT_OFF (38ull * MB)    // V^T [1024][8192] f16 = 16 MiB
#define PH_OFF (54ull * MB)    // P [8192][8192] f16 = 128 MiB
#define LP2_OFF (182ull * MB)  // lpart [128][8192] f32 = 4 MiB
#define LI_OFF (186ull * MB)   // linv [8192] f32

__device__ __forceinline__ half8 cvt8(float4 a, float4 b) {
  half8 h;
  h[0] = (f16)a.x; h[1] = (f16)a.y; h[2] = (f16)a.z; h[3] = (f16)a.w;
  h[4] = (f16)b.x; h[5] = (f16)b.y; h[6] = (f16)b.z; h[7] = (f16)b.w;
  return h;
}

// async global->LDS, 16B/lane; LDS dst = wave-uniform byte offset (+lane*16 by HW)
__device__ __forceinline__ void gload16(const void* g, uint32_t lds_off) {
  __builtin_amdgcn_global_load_lds(
      (__attribute__((address_space(1))) void*)(uintptr_t)g,
      (__attribute__((address_space(3))) void*)lds_off, 16, 0, 0);
}

// ------------------------------------------------------------------
// K1: transpose-cast weights: Wt[z][dout][din] = (f16)W_z[din][dout]
// ------------------------------------------------------------------
__global__ void k_wt(const float* __restrict__ Wq, const float* __restrict__ Wk,
                     const float* __restrict__ Wv, f16* __restrict__ Wt) {
  __shared__ float tile[32][33];
  const int z = blockIdx.z;
  const float* W = (z == 0) ? Wq : ((z == 1) ? Wk : Wv);
  f16* dst = Wt + z * (1024 * 1024);
  const int tx = threadIdx.x, ty = threadIdx.y;
  const int r0 = blockIdx.y * 32, c0 = blockIdx.x * 32;
#pragma unroll
  for (int i = 0; i < 32; i += 8)
    tile[ty + i][tx] = W[(r0 + ty + i) * 1024 + c0 + tx];
  __syncthreads();
#pragma unroll
  for (int i = 0; i < 32; i += 8)
    dst[(c0 + ty + i) * 1024 + r0 + tx] = (f16)tile[tx][ty + i];
}

// ------------------------------------------------------------------
// K2: projection GEMM (fp32 X cast on the fly). Proven in R2; unchanged.
// ------------------------------------------------------------------
__launch_bounds__(256, 2)
__global__ void k_proj(const float* __restrict__ X, const f16* __restrict__ Wt,
                       f16* __restrict__ Qh, f16* __restrict__ Kh, f16* __restrict__ Vt) {
  __shared__ f16 As[2][128][40];
  __shared__ f16 Bs[2][128][40];
  const int z = blockIdx.z;
  const f16* Wz = Wt + z * (1024 * 1024);
  const int m0 = blockIdx.x * 128, n0 = blockIdx.y * 128;
  const int t = threadIdx.x;
  const int w = t >> 6, l = t & 63;
  const int wr = w >> 1, wc = w & 1;
  const int lr = l & 15, lk = (l >> 4) * 8;
  const int sr = t >> 1, sh = t & 1;

  const float* xsrc = X + (m0 + sr) * 1024 + sh * 16;
  const f16*   bsrc = Wz + (n0 + sr) * 1024 + sh * 16;

  f32x4 acc[4][4] = {};

  {
    float4 v0 = *(const float4*)(xsrc + 0);
    float4 v1 = *(const float4*)(xsrc + 4);
    float4 v2 = *(const float4*)(xsrc + 8);
    float4 v3 = *(const float4*)(xsrc + 12);
    *(half8*)(&As[0][sr][sh * 16 + 0]) = cvt8(v0, v1);
    *(half8*)(&As[0][sr][sh * 16 + 8]) = cvt8(v2, v3);
    *(half8*)(&Bs[0][sr][sh * 16 + 0]) = *(const half8*)(bsrc + 0);
    *(half8*)(&Bs[0][sr][sh * 16 + 8]) = *(const half8*)(bsrc + 8);
  }
  __syncthreads();

#pragma unroll 1
  for (int kt = 0; kt < 32; ++kt) {
    const int cur = kt & 1;
    float4 v0, v1, v2, v3;
    half8 b0, b1;
    if (kt < 31) {
      const float* xs = xsrc + (kt + 1) * 32;
      v0 = *(const float4*)(xs + 0);
      v1 = *(const float4*)(xs + 4);
      v2 = *(const float4*)(xs + 8);
      v3 = *(const float4*)(xs + 12);
      const f16* bs = bsrc + (kt + 1) * 32;
      b0 = *(const half8*)(bs + 0);
      b1 = *(const half8*)(bs + 8);
    }
    half8 af[4], bf[4];
#pragma unroll
    for (int mi = 0; mi < 4; ++mi)
      af[mi] = *(const half8*)(&As[cur][wr * 64 + mi * 16 + lr][lk]);
#pragma unroll
    for (int ni = 0; ni < 4; ++ni)
      bf[ni] = *(const half8*)(&Bs[cur][wc * 64 + ni * 16 + lr][lk]);
#pragma unroll
    for (int mi = 0; mi < 4; ++mi)
#pragma unroll
      for (int ni = 0; ni < 4; ++ni)
        acc[mi][ni] = __builtin_amdgcn_mfma_f32_16x16x32_f16(af[mi], bf[ni], acc[mi][ni], 0, 0, 0);
    if (kt < 31) {
      *(half8*)(&As[cur ^ 1][sr][sh * 16 + 0]) = cvt8(v0, v1);
      *(half8*)(&As[cur ^ 1][sr][sh * 16 + 8]) = cvt8(v2, v3);
      *(half8*)(&Bs[cur ^ 1][sr][sh * 16 + 0]) = b0;
      *(half8*)(&Bs[cur ^ 1][sr][sh * 16 + 8]) = b1;
    }
    __syncthreads();
  }

  if (z < 2) {
    f16* dst = (z == 0) ? Qh : Kh;
#pragma unroll
    for (int mi = 0; mi < 4; ++mi)
#pragma unroll
      for (int ni = 0; ni < 4; ++ni) {
        const int row = m0 + wr * 64 + mi * 16 + (l >> 4) * 4;
        const int col = n0 + wc * 64 + ni * 16 + lr;
#pragma unroll
        for (int r = 0; r < 4; ++r)
          dst[(row + r) * 1024 + col] = (f16)acc[mi][ni][r];
      }
  } else {
#pragma unroll
    for (int mi = 0; mi < 4; ++mi)
#pragma unroll
      for (int ni = 0; ni < 4; ++ni) {
        const int row = m0 + wr * 64 + mi * 16 + (l >> 4) * 4;
        const int col = n0 + wc * 64 + ni * 16 + lr;
        half4v v = {(f16)acc[mi][ni][0], (f16)acc[mi][ni][1],
                    (f16)acc[mi][ni][2], (f16)acc[mi][ni][3]};
        *(half4v*)(&Vt[col * 8192 + row]) = v;
      }
  }
}

// ------------------------------------------------------------------
// K3: S = Q@K^T -> P = exp(S/32), m201-style P=4 schedule.
// BM=BN=256, BK=64 (2 ks x 32k), 8 waves 2x4, wave tile 128x64.
// 4 phases/K-tile = one 64x64 C-quadrant x one ks each (16 MFMA);
// B-frags read at mh=0 phases, reused at mh=1 (m201's 8/4 alternation).
// Per phase: ds_read | stage ONE region (2 gload16) | vmcnt(10) | barrier |
// setprio(1) 16 MFMA setprio(0) | barrier.  Stage->read distance 6 phases;
// vmcnt(10) = 5 phases x 2 gloads in flight. Swizzle: (row>>1)&3 (R4-verified).
// ------------------------------------------------------------------
__launch_bounds__(512, 2)
__global__ void k_s4(const f16* __restrict__ Qh, const f16* __restrict__ Kh,
                     f16* __restrict__ Ph, float* __restrict__ lpart) {
  constexpr int BBASE = 65536;
  __shared__ __align__(128) char smem[131072];
  const int t = threadIdx.x;
  const int w = t >> 6, l = t & 63;
  const int lr = l & 15, g = l >> 4;
  const int wr = w >> 2, wc = w & 3;              // 2 x 4 wave grid
  const int bid = blockIdx.x;
  const int swz = (bid & 7) * 128 + (bid >> 3);   // XCD-aware, nwg=1024
  const int mt = swz >> 5, ntl = swz & 31;
  const int m0 = mt << 8, n0 = ntl << 8;

  const uint32_t lds0 = (uint32_t)(uintptr_t)(void*)smem;
  const int lq = l >> 2, ls = l & 3;
  const int sw = (ls ^ ((lq >> 1) & 3)) << 3;     // pre-swizzled source k-off (halves)
  const int rdsw = (g ^ ((lr >> 1) & 3)) << 4;    // swizzled read slot (bytes)

  auto stA = [&](int kS, int ks, int b) {
#pragma unroll
    for (int j = 0; j < 2; ++j) {
      const int rl = w * 32 + j * 16 + lq;
      gload16(Qh + (size_t)(m0 + rl) * 1024 + kS * 64 + ks * 32 + sw,
              lds0 + b * 32768 + ks * 16384 + (w * 2 + j) * 1024);
    }
  };
  auto stB = [&](int kS, int ks, int b) {
#pragma unroll
    for (int j = 0; j < 2; ++j) {
      const int rl = w * 32 + j * 16 + lq;
      gload16(Kh + (size_t)(n0 + rl) * 1024 + kS * 64 + ks * 32 + sw,
              lds0 + BBASE + b * 32768 + ks * 16384 + (w * 2 + j) * 1024);
    }
  };

  f32x4 acc[8][4] = {};

  auto rdA = [&](int b, int ks, int mh, half8* af) {
#pragma unroll
    for (int mi = 0; mi < 4; ++mi)
      af[mi] = *(const half8*)(smem + b * 32768 + ks * 16384 +
                               (wr * 128 + mh * 64 + mi * 16 + lr) * 64 + rdsw);
  };
  auto rdB = [&](int b, int ks, half8* bf) {
#pragma unroll
    for (int ni = 0; ni < 4; ++ni)
      bf[ni] = *(const half8*)(smem + BBASE + b * 32768 + ks * 16384 +
                               (wc * 64 + ni * 16 + lr) * 64 + rdsw);
  };

#define VMW asm volatile("s_waitcnt vmcnt(10)")
#define BAR __builtin_amdgcn_s_barrier()
#define PR1 __builtin_amdgcn_s_setprio(1)
#define PR0 __builtin_amdgcn_s_setprio(0)

  // prologue: kt0 all 4 regions + kt1 {B_ks0, A_ks0, B_ks1}; kt0.j0 adds A1_ks1
  stA(0, 0, 0); stB(0, 0, 0);
  stA(0, 1, 0); stB(0, 1, 0);
  stB(1, 0, 1); stA(1, 0, 1); stB(1, 1, 1);
  VMW;  // oldest 4 (A[0][0], B[0][0]) retired
  BAR;

#pragma unroll 1
  for (int kt = 0; kt < 16; ++kt) {
    const int b = kt & 1;
    const int k1 = (kt + 1 < 16) ? kt + 1 : 15;  // clamped idempotent tail
    const int k2 = (kt + 2 < 16) ? kt + 2 : 15;
    half8 af[4], bf[4];
    // ---- j0: ks0, m-half 0 ----
    rdA(b, 0, 0, af); rdB(b, 0, bf);
    stA(k1, 1, b ^ 1);
    VMW; BAR; PR1;
#pragma unroll
    for (int mi = 0; mi < 4; ++mi)
#pragma unroll
      for (int ni = 0; ni < 4; ++ni)
        acc[mi][ni] = __builtin_amdgcn_mfma_f32_16x16x32_f16(af[mi], bf[ni], acc[mi][ni], 0, 0, 0);
    PR0; BAR;
    // ---- j1: ks0, m-half 1 (reuse bf) ----
    rdA(b, 0, 1, af);
    stB(k2, 0, b);
    VMW; BAR; PR1;
#pragma unroll
    for (int mi = 0; mi < 4; ++mi)
#pragma unroll
      for (int ni = 0; ni < 4; ++ni)
        acc[4 + mi][ni] = __builtin_amdgcn_mfma_f32_16x16x32_f16(af[mi], bf[ni], acc[4 + mi][ni], 0, 0, 0);
    PR0; BAR;
    // ---- j2: ks1, m-half 0 ----
    rdA(b, 1, 0, af); rdB(b, 1, bf);
    stA(k2, 0, b);
    VMW; BAR; PR1;
#pragma unroll
    for (int mi = 0; mi < 4; ++mi)
#pragma unroll
      for (int ni = 0; ni < 4; ++ni)
        acc[mi][ni] = __builtin_amdgcn_mfma_f32_16x16x32_f16(af[mi], bf[ni], acc[mi][ni], 0, 0, 0);
    PR0; BAR;
    // ---- j3: ks1, m-half 1 (reuse bf) ----
    rdA(b, 1, 1, af);
    stB(k2, 1, b);
    VMW; BAR; PR1;
#pragma unroll
    for (int mi = 0; mi < 4; ++mi)
#pragma unroll
      for (int ni = 0; ni < 4; ++ni)
        acc[4 + mi][ni] = __builtin_amdgcn_mfma_f32_16x16x32_f16(af[mi], bf[ni], acc[4 + mi][ni], 0, 0, 0);
    PR0; BAR;
  }
  asm volatile("s_waitcnt vmcnt(0)");  // drain tail DMA before LDS reuse
  BAR;

  // ---- epilogue: p = exp2(S*log2e/32); row partials; P tile via LDS ----
  float rs[8][4];
#pragma unroll
  for (int mi = 0; mi < 8; ++mi)
#pragma unroll
    for (int r = 0; r < 4; ++r) rs[mi][r] = 0.f;
#pragma unroll
  for (int mi = 0; mi < 8; ++mi)
#pragma unroll
    for (int ni = 0; ni < 4; ++ni)
#pragma unroll
      for (int r = 0; r < 4; ++r) {
        const float p = exp2f(acc[mi][ni][r] * 0.045084222f);
        acc[mi][ni][r] = p;
        rs[mi][r] += p;
      }
#pragma unroll
  for (int mi = 0; mi < 8; ++mi)
#pragma unroll
    for (int r = 0; r < 4; ++r) {
      float v = rs[mi][r];
      v += __shfl_xor(v, 1); v += __shfl_xor(v, 2);
      v += __shfl_xor(v, 4); v += __shfl_xor(v, 8);
      rs[mi][r] = v;
    }
  if (lr == 0) {
#pragma unroll
    for (int mi = 0; mi < 8; ++mi)
#pragma unroll
      for (int r = 0; r < 4; ++r)
        lpart[(size_t)(ntl * 4 + wc) * 8192 + m0 + wr * 128 + mi * 16 + g * 4 + r] = rs[mi][r];
  }
#pragma unroll
  for (int mi = 0; mi < 8; ++mi)
#pragma unroll
    for (int ni = 0; ni < 4; ++ni)
#pragma unroll
      for (int r = 0; r < 4; ++r)
        *(f16*)(smem + (wr * 128 + mi * 16 + g * 4 + r) * 512 +
                (wc * 64 + ni * 16 + lr) * 2) = (f16)acc[mi][ni][r];
  __syncthreads();
  {
    const int row = t >> 1, sl = t & 1;
#pragma unroll
    for (int q = 0; q < 16; ++q)
      *(int4*)(Ph + (size_t)(m0 + row) * 8192 + n0 + sl * 128 + q * 8) =
          *(const int4*)(smem + row * 512 + sl * 256 + q * 16);
  }
#undef VMW
#undef BAR
#undef PR1
#undef PR0
}

// ------------------------------------------------------------------
// K5 (pv): unified P=2 deep-pipeline GEMM — unchanged from R4.
// ------------------------------------------------------------------
template <int WN, int BN, int NK, int LDA, int LDB, bool PVE>
__launch_bounds__(512, 2)
__global__ void k_g8(const f16* __restrict__ Ag, const f16* __restrict__ Bg,
                     f16* __restrict__ Pg, float* __restrict__ lpart,
                     const float* __restrict__ linv, float* __restrict__ outp) {
  constexpr int WM = 8 / WN;
  constexpr int WTM = 256 / WM;
  constexpr int NRM = WTM / 16;
  constexpr int BKS = BN * 64;
  constexpr int NLB = BN / 128;
  constexpr int BBASE = 65536;
  constexpr int VM = 2 * (2 + NLB);
  constexpr int NTN = (PVE ? 1024 : 8192) / BN;
  constexpr int CPX = (32 * NTN) / 8;

  __shared__ __align__(128) char smem[BBASE + 4 * BKS];

  const int t = threadIdx.x;
  const int w = t >> 6, l = t & 63;
  const int lr = l & 15, g = l >> 4;
  const int wr = w / WN, wc = w % WN;
  const int bid = blockIdx.x;
  const int swz = (bid & 7) * CPX + (bid >> 3);
  const int mt = swz / NTN, ntl = swz % NTN;
  const int m0 = mt * 256, n0 = ntl * BN;

  const uint32_t lds0 = (uint32_t)(uintptr_t)(void*)smem;
  const int lq = l >> 2, ls = l & 3;
  const int sw = (ls ^ ((lq >> 1) & 3)) << 3;
  const int rdsw = (g ^ ((lr >> 1) & 3)) << 4;

  auto stA = [&](int kS, int ks, int b) {
#pragma unroll
    for (int j = 0; j < 2; ++j) {
      const int rl = w * 32 + j * 16 + lq;
      gload16(Ag + (size_t)(m0 + rl) * LDA + kS * 64 + ks * 32 + sw,
              lds0 + b * 32768 + ks * 16384 + (w * 2 + j) * 1024);
    }
  };
  auto stB = [&](int kS, int ks, int b) {
#pragma unroll
    for (int j = 0; j < NLB; ++j) {
      const int rl = w * (16 * NLB) + j * 16 + lq;
      gload16(Bg + (size_t)(n0 + rl) * LDB + kS * 64 + ks * 32 + sw,
              lds0 + BBASE + b * (2 * BKS) + ks * BKS + (w * NLB + j) * 1024);
    }
  };

  f32x4 acc[NRM][4] = {};

  stA(0, 0, 0); stB(0, 0, 0);
  stA(0, 1, 0); stB(0, 1, 0);
  stA(1, 0, 1); stB(1, 0, 1);
  asm volatile("s_waitcnt vmcnt(%0)" :: "i"(VM));
  __builtin_amdgcn_s_barrier();

#pragma unroll 1
  for (int kt = 0; kt < NK; ++kt) {
    const int b = kt & 1;
    const int k1 = (kt + 1 < NK) ? kt + 1 : kt;
    const int k2 = (kt + 2 < NK) ? kt + 2 : kt;
#pragma unroll
    for (int ks = 0; ks < 2; ++ks) {
      half8 af[NRM], bf[4];
#pragma unroll
      for (int mi = 0; mi < NRM; ++mi)
        af[mi] = *(const half8*)(smem + b * 32768 + ks * 16384 +
                                 (wr * WTM + mi * 16 + lr) * 64 + rdsw);
#pragma unroll
      for (int ni = 0; ni < 4; ++ni)
        bf[ni] = *(const half8*)(smem + BBASE + b * (2 * BKS) + ks * BKS +
                                 (wc * 64 + ni * 16 + lr) * 64 + rdsw);
      if (ks == 0) { stA(k1, 1, b ^ 1); stB(k1, 1, b ^ 1); }
      else         { stA(k2, 0, b);     stB(k2, 0, b); }
      asm volatile("s_waitcnt vmcnt(%0)" :: "i"(VM));
      __builtin_amdgcn_s_barrier();
      __builtin_amdgcn_s_setprio(1);
#pragma unroll
      for (int mi = 0; mi < NRM; ++mi)
#pragma unroll
        for (int ni = 0; ni < 4; ++ni)
          acc[mi][ni] = __builtin_amdgcn_mfma_f32_16x16x32_f16(af[mi], bf[ni], acc[mi][ni], 0, 0, 0);
      __builtin_amdgcn_s_setprio(0);
      __builtin_amdgcn_s_barrier();
    }
  }
  asm volatile("s_waitcnt vmcnt(0)");
  __builtin_amdgcn_s_barrier();

  if constexpr (!PVE) {
    float rs[NRM][4];
#pragma unroll
    for (int mi = 0; mi < NRM; ++mi)
#pragma unroll
      for (int r = 0; r < 4; ++r) rs[mi][r] = 0.f;
#pragma unroll
    for (int mi = 0; mi < NRM; ++mi)
#pragma unroll
      for (int ni = 0; ni < 4; ++ni)
#pragma unroll
        for (int r = 0; r < 4; ++r) {
          const float p = exp2f(acc[mi][ni][r] * 0.045084222f);
          acc[mi][ni][r] = p;
          rs[mi][r] += p;
        }
#pragma unroll
    for (int mi = 0; mi < NRM; ++mi)
#pragma unroll
      for (int r = 0; r < 4; ++r) {
        float v = rs[mi][r];
        v += __shfl_xor(v, 1); v += __shfl_xor(v, 2);
        v += __shfl_xor(v, 4); v += __shfl_xor(v, 8);
        rs[mi][r] = v;
      }
    if (lr == 0) {
#pragma unroll
      for (int mi = 0; mi < NRM; ++mi)
#pragma unroll
        for (int r = 0; r < 4; ++r)
          lpart[(size_t)(ntl * WN + wc) * 8192 + m0 + wr * WTM + mi * 16 + g * 4 + r] = rs[mi][r];
    }
#pragma unroll
    for (int mi = 0; mi < NRM; ++mi)
#pragma unroll
      for (int ni = 0; ni < 4; ++ni)
#pragma unroll
        for (int r = 0; r < 4; ++r)
          *(f16*)(smem + (wr * WTM + mi * 16 + g * 4 + r) * 512 +
                  (wc * 64 + ni * 16 + lr) * 2) = (f16)acc[mi][ni][r];
    __syncthreads();
    {
      const int row = t >> 1, sl = t & 1;
#pragma unroll
      for (int q = 0; q < 16; ++q)
        *(int4*)(Pg + (size_t)(m0 + row) * 8192 + n0 + sl * 128 + q * 8) =
            *(const int4*)(smem + row * 512 + sl * 256 + q * 16);
    }
  } else {
#pragma unroll
    for (int mi = 0; mi < NRM; ++mi) {
#pragma unroll
      for (int r = 0; r < 4; ++r) {
        const int rowg = m0 + wr * WTM + mi * 16 + g * 4 + r;
        const float iv = linv[rowg];
#pragma unroll
        for (int ni = 0; ni < 4; ++ni)
          outp[(size_t)rowg * 1024 + n0 + wc * 64 + ni * 16 + lr] = acc[mi][ni][r] * iv;
      }
    }
  }
}

// ------------------------------------------------------------------
// K4: reduce 128 row-sum partials -> inverse row sums
// ------------------------------------------------------------------
__global__ void k_lred(const float* __restrict__ lpart, float* __restrict__ linv) {
  const int r = blockIdx.x * 256 + threadIdx.x;
  float s = 0.f;
#pragma unroll
  for (int i = 0; i < 128; ++i) s += lpart[(size_t)i * 8192 + r];
  linv[r] = 1.0f / s;
}

// ------------------------------------------------------------------
extern "C" void kernel_launch(void* const* d_in, const int* in_sizes, int n_in,
                              void* d_out, int out_size, void* d_ws, size_t ws_size,
                              hipStream_t stream) {
  (void)in_sizes; (void)n_in; (void)out_size; (void)ws_size;
  const float* X  = (const float*)d_in[0];
  const float* Wq = (const float*)d_in[1];
  const float* Wk = (const float*)d_in[2];
  const float* Wv = (const float*)d_in[3];
  char* ws = (char*)d_ws;
  f16* Wt = (f16*)(ws + WT_OFF);
  f16* Qh = (f16*)(ws + QH_OFF);
  f16* Kh = (f16*)(ws + KH_OFF);
  f16* Vt = (f16*)(ws + VT_OFF);
  f16* Ph = (f16*)(ws + PH_OFF);
  float* lpart = (float*)(ws + LP2_OFF);
  float* linv  = (float*)(ws + LI_OFF);
  float* out = (float*)d_out;

  k_wt  <<<dim3(32, 32, 3), dim3(32, 8), 0, stream>>>(Wq, Wk, Wv, Wt);
  k_proj<<<dim3(64, 8, 3),  dim3(256),   0, stream>>>(X, Wt, Qh, Kh, Vt);
  // S = Q@K^T -> P = exp(S/32): M=N=8192, K=1024; 32x32 tiles of 256^2
  k_s4<<<dim3(1024), dim3(512), 0, stream>>>(Qh, Kh, Ph, lpart);
  k_lred<<<dim3(32), dim3(256), 0, stream>>>(lpart, linv);
  // out = (P@V) * linv: M=8192, N=1024, K=8192; 32x8 tiles of 256x128
  k_g8<2, 128, 128, 8192, 8192, true><<<dim3(256), dim3(512), 0, stream>>>(
      Ph, Vt, nullptr, nullptr, linv, out);
}